// Round 1
// 577.865 us; speedup vs baseline: 1.1235x; 1.1235x over previous
//
#include <hip/hip_runtime.h>
#include <hip/hip_bf16.h>

// Problem constants
#define Bn 128
#define Tn 64
#define Dn 1024
#define Hn 16
#define HDn 64

typedef __bf16 bf16_t;
typedef __bf16 bf16x8 __attribute__((ext_vector_type(8)));
typedef float f32x4 __attribute__((ext_vector_type(4)));

__device__ __forceinline__ f32x4 mfma16(bf16x8 a, bf16x8 b, f32x4 c) {
  return __builtin_amdgcn_mfma_f32_16x16x32_bf16(a, b, c, 0, 0, 0);
}

// load 8 consecutive fp32, round to bf16 fragment
__device__ __forceinline__ bf16x8 ld8f(const float* p) {
  float4 a = *(const float4*)p;
  float4 b = *(const float4*)(p + 4);
  bf16x8 r;
  r[0] = (bf16_t)a.x; r[1] = (bf16_t)a.y; r[2] = (bf16_t)a.z; r[3] = (bf16_t)a.w;
  r[4] = (bf16_t)b.x; r[5] = (bf16_t)b.y; r[6] = (bf16_t)b.z; r[7] = (bf16_t)b.w;
  return r;
}

// ---------------------------------------------------------------------------
// K-1: fp32 -> bf16 bulk convert (for x). 8 elems/thread.
// ---------------------------------------------------------------------------
__global__ __launch_bounds__(256) void convert_bf16(const float* __restrict__ src,
                                                    bf16_t* __restrict__ dst) {
  long i = ((long)blockIdx.x * 256 + threadIdx.x) * 8;
  *(bf16x8*)(dst + i) = ld8f(src + i);
}

// ---------------------------------------------------------------------------
// K0: 1024x1024 transpose + fp32->bf16 (weights): Wt[n][k] = W[k][n]
// ---------------------------------------------------------------------------
__global__ __launch_bounds__(256) void transpose_mat(const float* __restrict__ W,
                                                     bf16_t* __restrict__ Wt) {
  __shared__ bf16_t tile[64][65];
  const int tr = blockIdx.y, tc = blockIdx.x;
  const int t = threadIdx.x;
#pragma unroll
  for (int i = 0; i < 16; i++) {
    int idx = t + i * 256;
    int r = idx >> 6, c = idx & 63;
    tile[r][c] = (bf16_t)W[(long)(tr * 64 + r) * 1024 + tc * 64 + c];
  }
  __syncthreads();
#pragma unroll
  for (int i = 0; i < 16; i++) {
    int idx = t + i * 256;
    int c = idx >> 6, r = idx & 63;
    Wt[(long)(tc * 64 + c) * 1024 + tr * 64 + r] = tile[r][c];
  }
}

// ---------------------------------------------------------------------------
// K1/K5: C[M,N] = A[M,K] @ Bt[N,K]^T  (bf16 in, fp32 acc, CT out)
// 128x128 tile, BK=64, 4 waves each computing a 64x64 quadrant.
// ---------------------------------------------------------------------------
template <typename CT>
__global__ __launch_bounds__(256) void gemm_bt(const bf16_t* __restrict__ A,
                                               const bf16_t* __restrict__ Bt,
                                               CT* __restrict__ C,
                                               int M, int N, int K) {
  __shared__ bf16_t As[128 * 64];
  __shared__ bf16_t Bs[128 * 64];
  const int t = threadIdx.x;
  const int w = t >> 6, lane = t & 63;
  const int l16 = lane & 15, quad = lane >> 4;
  const int m0 = blockIdx.y * 128, n0 = blockIdx.x * 128;
  const int wm = (w >> 1) * 64, wn = (w & 1) * 64;

  f32x4 acc[4][4];
#pragma unroll
  for (int i = 0; i < 4; i++)
#pragma unroll
    for (int j = 0; j < 4; j++) acc[i][j] = (f32x4){0.f, 0.f, 0.f, 0.f};

  const int sr = t >> 3;         // 0..31: row within 32-row group
  const int sc = (t & 7) * 8;    // col (element) within 64

  for (int k0 = 0; k0 < K; k0 += 64) {
    __syncthreads();
#pragma unroll
    for (int i = 0; i < 4; i++) {
      int row = i * 32 + sr;
      *(bf16x8*)(As + row * 64 + sc) =
          *(const bf16x8*)(A + (long)(m0 + row) * K + k0 + sc);
      *(bf16x8*)(Bs + row * 64 + sc) =
          *(const bf16x8*)(Bt + (long)(n0 + row) * K + k0 + sc);
    }
    __syncthreads();
#pragma unroll
    for (int kk = 0; kk < 64; kk += 32) {
      bf16x8 af[4], bfr[4];
#pragma unroll
      for (int i = 0; i < 4; i++)
        af[i] = *(const bf16x8*)(As + (wm + i * 16 + l16) * 64 + kk + quad * 8);
#pragma unroll
      for (int j = 0; j < 4; j++)
        bfr[j] = *(const bf16x8*)(Bs + (wn + j * 16 + l16) * 64 + kk + quad * 8);
#pragma unroll
      for (int i = 0; i < 4; i++)
#pragma unroll
        for (int j = 0; j < 4; j++) acc[i][j] = mfma16(af[i], bfr[j], acc[i][j]);
    }
  }
#pragma unroll
  for (int i = 0; i < 4; i++)
#pragma unroll
    for (int j = 0; j < 4; j++) {
      int col = n0 + wn + j * 16 + l16;
#pragma unroll
      for (int r = 0; r < 4; r++) {
        int row = m0 + wm + i * 16 + quad * 4 + r;
        C[(long)row * N + col] = (CT)acc[i][j][r];
      }
    }
}

// ---------------------------------------------------------------------------
// FUSED: per (b, q-tile of 16): all three logits terms accumulated in LDS
// (fp32, pad-65), softmax, P@a_v. Writes probs (bf16) + out2 (bf16).
// 1024 threads = 16 waves. Grid 512 (XCD-swizzled so each XCD owns 16 b's).
//
// Phases (barriers only between cross-wave LDS accumulation):
//   cc  : wave w = head h   : L[q][h][k]  = 0.125 * Q[q,h,:].K[k,h,:]
//   aq  : wave w = k-slice  : L[q][h][k] += a_q[q,k,:].K[k,h,:]
//   ak  : wave w = q        : L[q][h][k] += Q[q,h,:].a_k[q,k,:]
//   sm  : 4 thr per (q,h) row; exp kept in regs; P -> global + LDS (swizzled)
//   pav : wave w = q        : out2[q,h,:] = P[q,h,:] @ a_v[q,:,:]
// softmax->pav needs NO barrier: wave w touches only its own 16 rows.
// ---------------------------------------------------------------------------
__global__ __launch_bounds__(1024) void fused_att(
    const bf16_t* __restrict__ Qb, const bf16_t* __restrict__ Kb,
    const float* __restrict__ aqp, const float* __restrict__ akp,
    const float* __restrict__ avp,
    bf16_t* __restrict__ probs, bf16_t* __restrict__ out2) {
  __shared__ float Ls[256 * 65];      // logits [row=q*16+h][k], pad 65 (66.5KB)
  __shared__ bf16_t Pb[256 * 64];     // probs, k-chunk XOR-swizzled (32KB)

  const int id = blockIdx.x;
  const int b = (id & 7) * 16 + ((id >> 3) & 15);  // bijective XCD swizzle
  const int q0 = (id >> 7) * 16;                   // q-tile origin: 0,16,32,48
  const int t = threadIdx.x;
  const int w = t >> 6, lane = t & 63, l16 = lane & 15, quad = lane >> 4;

  // ---- phase cc: head h = w --------------------------------------------
  {
    const int h = w;
    f32x4 acc[4];
#pragma unroll
    for (int j = 0; j < 4; j++) acc[j] = (f32x4){0.f, 0.f, 0.f, 0.f};
    const bf16_t* qb = Qb + (long)(b * Tn + q0 + l16) * Dn + h * HDn;
    const bf16_t* kb = Kb + (long)b * (Tn * Dn) + h * HDn;
#pragma unroll
    for (int kk = 0; kk < 64; kk += 32) {
      bf16x8 af = *(const bf16x8*)(qb + kk + quad * 8);
#pragma unroll
      for (int j = 0; j < 4; j++) {
        bf16x8 bf = *(const bf16x8*)(kb + (long)(j * 16 + l16) * Dn + kk + quad * 8);
        acc[j] = mfma16(af, bf, acc[j]);
      }
    }
#pragma unroll
    for (int j = 0; j < 4; j++)
#pragma unroll
      for (int r = 0; r < 4; r++)
        Ls[((quad * 4 + r) * 16 + h) * 65 + j * 16 + l16] = 0.125f * acc[j][r];
  }
  __syncthreads();

  // ---- phase aq: k = w*4 .. w*4+3 --------------------------------------
  {
    const float* ab = aqp + (long)(b * Tn + q0 + l16) * (Tn * HDn);
    const bf16_t* kb = Kb + (long)b * (Tn * Dn) + l16 * HDn;  // h = l16
#pragma unroll
    for (int kc = 0; kc < 4; kc++) {
      const int k = w * 4 + kc;
      f32x4 acc = (f32x4){0.f, 0.f, 0.f, 0.f};
#pragma unroll
      for (int kk = 0; kk < 64; kk += 32) {
        bf16x8 af = ld8f(ab + k * HDn + kk + quad * 8);
        bf16x8 bf = *(const bf16x8*)(kb + (long)k * Dn + kk + quad * 8);
        acc = mfma16(af, bf, acc);
      }
#pragma unroll
      for (int r = 0; r < 4; r++)
        Ls[((quad * 4 + r) * 16 + l16) * 65 + k] += acc[r];
    }
  }
  __syncthreads();

  // ---- phase ak: q = w --------------------------------------------------
  {
    const int q = w;
    const bf16_t* qb = Qb + (long)(b * Tn + q0 + q) * Dn + l16 * HDn;  // h = l16
    const float* ab = akp + (long)(b * Tn + q0 + q) * (Tn * HDn);
    f32x4 acc[4];
#pragma unroll
    for (int j = 0; j < 4; j++) acc[j] = (f32x4){0.f, 0.f, 0.f, 0.f};
#pragma unroll
    for (int kk = 0; kk < 64; kk += 32) {
      bf16x8 af = *(const bf16x8*)(qb + kk + quad * 8);
#pragma unroll
      for (int j = 0; j < 4; j++) {
        bf16x8 bf = ld8f(ab + (long)(j * 16 + l16) * HDn + kk + quad * 8);
        acc[j] = mfma16(af, bf, acc[j]);
      }
    }
#pragma unroll
    for (int j = 0; j < 4; j++)
#pragma unroll
      for (int r = 0; r < 4; r++)
        Ls[(q * 16 + quad * 4 + r) * 65 + j * 16 + l16] += acc[j][r];
  }
  __syncthreads();

  // ---- softmax: row r = t>>2 (q = r>>4, h = r&15), k-range (t&3)*16 ----
  {
    const int r = t >> 2, qq = t & 3;
    const int q = r >> 4, h = r & 15;
    const float* row = Ls + r * 65 + qq * 16;
    float m = -1e30f;
#pragma unroll
    for (int i = 0; i < 16; i++) m = fmaxf(m, row[i]);
    m = fmaxf(m, __shfl_xor(m, 1));
    m = fmaxf(m, __shfl_xor(m, 2));
    float e[16];
    float s = 0.f;
#pragma unroll
    for (int i = 0; i < 16; i++) { e[i] = __expf(row[i] - m); s += e[i]; }
    s += __shfl_xor(s, 1);
    s += __shfl_xor(s, 2);
    const float inv = 1.0f / s;
    const int swz = (q ^ h) & 7;
    bf16_t* pr = probs + ((long)(b * Hn + h) * Tn + q0 + q) * Tn + qq * 16;
#pragma unroll
    for (int c = 0; c < 2; c++) {
      bf16x8 v;
#pragma unroll
      for (int ee = 0; ee < 8; ee++) v[ee] = (bf16_t)(e[c * 8 + ee] * inv);
      *(bf16x8*)(pr + c * 8) = v;
      const int cg = qq * 2 + c;
      *(bf16x8*)(Pb + r * 64 + (cg ^ swz) * 8) = v;
    }
  }
  // NO barrier: wave w only consumes rows [16w,16w+16) it wrote itself.

  // ---- pav: q = w. avT reuses THIS WAVE'S dead Ls rows -----------------
  {
    const int q = w;
    bf16_t* avT = (bf16_t*)(Ls + 16 * w * 65);  // 4160B avail, 4096 used
    const float* src = avp + (long)(b * Tn + q0 + q) * (Tn * HDn) + lane * HDn;
    f32x4 acc[4];
#pragma unroll
    for (int j = 0; j < 4; j++) acc[j] = (f32x4){0.f, 0.f, 0.f, 0.f};
    const int aswz = (q ^ l16) & 7;
#pragma unroll
    for (int half = 0; half < 2; half++) {
      // drain own softmax LDS reads/writes before overwriting rows
      asm volatile("s_waitcnt lgkmcnt(0)" ::: "memory");
      // stage a_v[d = half*32+0..31][k=lane] -> avT (chunk-swizzled, bf16)
#pragma unroll
      for (int c = 0; c < 8; c++) {
        float4 v = *(const float4*)(src + half * 32 + c * 4);
#pragma unroll
        for (int ee = 0; ee < 4; ee++) {
          int dl = c * 4 + ee;
          avT[dl * 64 + (((lane >> 3) ^ dl) & 7) * 8 + (lane & 7)] =
              (bf16_t)(&v.x)[ee];
        }
      }
      asm volatile("s_waitcnt lgkmcnt(0)" ::: "memory");
      __builtin_amdgcn_sched_barrier(0);
#pragma unroll
      for (int kk = 0; kk < 64; kk += 32) {
        const int cg = (kk >> 3) + quad;
        bf16x8 af = *(const bf16x8*)(Pb + (q * 16 + l16) * 64 + (cg ^ aswz) * 8);
#pragma unroll
        for (int jj = 0; jj < 2; jj++) {
          int j = half * 2 + jj;
          int dl = jj * 16 + l16;  // d within this half
          bf16x8 bf = *(const bf16x8*)(avT + dl * 64 + ((cg ^ (dl & 7))) * 8);
          acc[j] = mfma16(af, bf, acc[j]);
        }
      }
    }
    bf16_t* ob = out2 + (long)(b * Tn + q0 + q) * Dn;
#pragma unroll
    for (int j = 0; j < 4; j++)
#pragma unroll
      for (int r = 0; r < 4; r++)
        ob[(quad * 4 + r) * HDn + j * 16 + l16] = (bf16_t)acc[j][r];
  }
}

// ---------------------------------------------------------------------------
// K4: per (b,h): attn[b,q,h,d] = probs[b,h] @ V[b,:,h,:] + out2[b,q,h,d]
// ---------------------------------------------------------------------------
__global__ __launch_bounds__(256) void pv_out(const bf16_t* __restrict__ probs,
                                              const bf16_t* __restrict__ V,
                                              const bf16_t* __restrict__ out2,
                                              bf16_t* __restrict__ attn) {
  const int h = blockIdx.x, b = blockIdx.y;
  __shared__ bf16_t VT[64][72];
  const int t = threadIdx.x, w = t >> 6, lane = t & 63;
  const int l16 = lane & 15, quad = lane >> 4;

  {  // V[b,k,h,d] -> VT[d][k]
    const bf16_t* src = V + (long)b * (Tn * Dn) + h * HDn;
    int k = t & 63, d0 = (t >> 6) * 16;
    union { uint4 u; unsigned short s[8]; } v0, v1;
    v0.u = *(const uint4*)(src + (long)k * Dn + d0);
    v1.u = *(const uint4*)(src + (long)k * Dn + d0 + 8);
    unsigned short* lds = (unsigned short*)&VT[0][0];
#pragma unroll
    for (int j = 0; j < 8; j++) lds[(d0 + j) * 72 + k] = v0.s[j];
#pragma unroll
    for (int j = 0; j < 8; j++) lds[(d0 + 8 + j) * 72 + k] = v1.s[j];
  }
  __syncthreads();

  const bf16_t* pbase = probs + ((long)(b * Hn + h) * Tn) * Tn;
  f32x4 acc[4];
#pragma unroll
  for (int j = 0; j < 4; j++) acc[j] = (f32x4){0.f, 0.f, 0.f, 0.f};
#pragma unroll
  for (int kk = 0; kk < 64; kk += 32) {
    bf16x8 af = *(const bf16x8*)(pbase + (long)(w * 16 + l16) * Tn + kk + quad * 8);
#pragma unroll
    for (int j = 0; j < 4; j++) {
      bf16x8 bfr = *(const bf16x8*)(&VT[j * 16 + l16][kk + quad * 8]);
      acc[j] = mfma16(af, bfr, acc[j]);
    }
  }
#pragma unroll
  for (int j = 0; j < 4; j++)
#pragma unroll
    for (int r = 0; r < 4; r++) {
      int qrow = w * 16 + quad * 4 + r, d = j * 16 + l16;
      long idx = (long)(b * Tn + qrow) * Dn + h * HDn + d;
      attn[idx] = (bf16_t)(acc[j][r] + (float)out2[idx]);
    }
}

// ---------------------------------------------------------------------------
extern "C" void kernel_launch(void* const* d_in, const int* in_sizes, int n_in,
                              void* d_out, int out_size, void* d_ws, size_t ws_size,
                              hipStream_t stream) {
  const float* x  = (const float*)d_in[0];
  const float* aq = (const float*)d_in[1];
  const float* ak = (const float*)d_in[2];
  const float* av = (const float*)d_in[3];
  const float* Wq = (const float*)d_in[4];
  const float* Wk = (const float*)d_in[5];
  const float* Wv = (const float*)d_in[6];
  const float* Wo = (const float*)d_in[7];
  float* out = (float*)d_out;

  char* ws = (char*)d_ws;
  const size_t MB = 1024 * 1024;
  bf16_t* WqT    = (bf16_t*)(ws + 0 * MB);     // 2MB each
  bf16_t* WkT    = (bf16_t*)(ws + 2 * MB);
  bf16_t* WvT    = (bf16_t*)(ws + 4 * MB);
  bf16_t* WoT    = (bf16_t*)(ws + 6 * MB);
  bf16_t* xb     = (bf16_t*)(ws + 8 * MB);     // [B,T,D] bf16 16MB
  bf16_t* Qb     = (bf16_t*)(ws + 24 * MB);    // [B,T,H,HD] 16MB
  bf16_t* Kb     = (bf16_t*)(ws + 40 * MB);
  bf16_t* Vb     = (bf16_t*)(ws + 56 * MB);
  bf16_t* probs  = (bf16_t*)(ws + 72 * MB);    // [B,H,T,T] 16MB
  bf16_t* out2   = (bf16_t*)(ws + 88 * MB);    // [B,T,H,HD] 16MB
  bf16_t* attn   = (bf16_t*)(ws + 104 * MB);   // [B,T,D] 16MB -> 120MB total

  dim3 blk(256);
  convert_bf16<<<dim3(4096), blk, 0, stream>>>(x, xb);
  transpose_mat<<<dim3(16, 16), blk, 0, stream>>>(Wq, WqT);
  transpose_mat<<<dim3(16, 16), blk, 0, stream>>>(Wk, WkT);
  transpose_mat<<<dim3(16, 16), blk, 0, stream>>>(Wv, WvT);
  transpose_mat<<<dim3(16, 16), blk, 0, stream>>>(Wo, WoT);

  gemm_bt<bf16_t><<<dim3(8, 64), blk, 0, stream>>>(xb, WqT, Qb, Bn * Tn, Dn, Dn);
  gemm_bt<bf16_t><<<dim3(8, 64), blk, 0, stream>>>(xb, WkT, Kb, Bn * Tn, Dn, Dn);
  gemm_bt<bf16_t><<<dim3(8, 64), blk, 0, stream>>>(xb, WvT, Vb, Bn * Tn, Dn, Dn);

  fused_att<<<dim3(512), dim3(1024), 0, stream>>>(Qb, Kb, aq, ak, av, probs, out2);

  pv_out<<<dim3(Hn, Bn), blk, 0, stream>>>(probs, Vb, out2, attn);

  gemm_bt<float><<<dim3(8, 64), blk, 0, stream>>>(attn, WoT, out, Bn * Tn, Dn, Dn);
}

// Round 2
// 566.269 us; speedup vs baseline: 1.1465x; 1.0205x over previous
//
#include <hip/hip_runtime.h>
#include <hip/hip_bf16.h>

// Problem constants
#define Bn 128
#define Tn 64
#define Dn 1024
#define Hn 16
#define HDn 64

typedef __bf16 bf16_t;
typedef __bf16 bf16x8 __attribute__((ext_vector_type(8)));
typedef float f32x4 __attribute__((ext_vector_type(4)));

__device__ __forceinline__ f32x4 mfma16(bf16x8 a, bf16x8 b, f32x4 c) {
  return __builtin_amdgcn_mfma_f32_16x16x32_bf16(a, b, c, 0, 0, 0);
}

// load 8 consecutive fp32, round to bf16 fragment
__device__ __forceinline__ bf16x8 ld8f(const float* p) {
  float4 a = *(const float4*)p;
  float4 b = *(const float4*)(p + 4);
  bf16x8 r;
  r[0] = (bf16_t)a.x; r[1] = (bf16_t)a.y; r[2] = (bf16_t)a.z; r[3] = (bf16_t)a.w;
  r[4] = (bf16_t)b.x; r[5] = (bf16_t)b.y; r[6] = (bf16_t)b.z; r[7] = (bf16_t)b.w;
  return r;
}

// async global->LDS 16B/lane. LDS dest must be wave-uniform base + lane*16.
__device__ __forceinline__ void gload16(const bf16_t* g, bf16_t* l) {
  __builtin_amdgcn_global_load_lds(
      (const __attribute__((address_space(1))) void*)g,
      (__attribute__((address_space(3))) void*)l, 16, 0, 0);
}

// ---------------------------------------------------------------------------
// K-1: fp32 -> bf16 bulk convert (for x). 8 elems/thread.
// ---------------------------------------------------------------------------
__global__ __launch_bounds__(256) void convert_bf16(const float* __restrict__ src,
                                                    bf16_t* __restrict__ dst) {
  long i = ((long)blockIdx.x * 256 + threadIdx.x) * 8;
  *(bf16x8*)(dst + i) = ld8f(src + i);
}

// ---------------------------------------------------------------------------
// K0: 1024x1024 transpose + fp32->bf16 (weights): Wt[n][k] = W[k][n]
// ---------------------------------------------------------------------------
__global__ __launch_bounds__(256) void transpose_mat(const float* __restrict__ W,
                                                     bf16_t* __restrict__ Wt) {
  __shared__ bf16_t tile[64][65];
  const int tr = blockIdx.y, tc = blockIdx.x;
  const int t = threadIdx.x;
#pragma unroll
  for (int i = 0; i < 16; i++) {
    int idx = t + i * 256;
    int r = idx >> 6, c = idx & 63;
    tile[r][c] = (bf16_t)W[(long)(tr * 64 + r) * 1024 + tc * 64 + c];
  }
  __syncthreads();
#pragma unroll
  for (int i = 0; i < 16; i++) {
    int idx = t + i * 256;
    int c = idx >> 6, r = idx & 63;
    Wt[(long)(tc * 64 + c) * 1024 + tr * 64 + r] = tile[r][c];
  }
}

// ---------------------------------------------------------------------------
// K1/K5: C[M,N] = A[M,K] @ Bt[N,K]^T  (bf16 in, fp32 acc, CT out)
// 128x128 tile, BK=64, 4 waves. Staging via global_load_lds (m97 pattern):
// LDS dest for wave w, slice i is As + (i*32 + w*8)*64 elems, +lane*16 bytes.
// ---------------------------------------------------------------------------
template <typename CT>
__global__ __launch_bounds__(256) void gemm_bt(const bf16_t* __restrict__ A,
                                               const bf16_t* __restrict__ Bt,
                                               CT* __restrict__ C,
                                               int M, int N, int K) {
  __shared__ bf16_t As[128 * 64];
  __shared__ bf16_t Bs[128 * 64];
  const int t = threadIdx.x;
  const int w = t >> 6, lane = t & 63;
  const int l16 = lane & 15, quad = lane >> 4;
  const int m0 = blockIdx.y * 128, n0 = blockIdx.x * 128;
  const int wm = (w >> 1) * 64, wn = (w & 1) * 64;

  f32x4 acc[4][4];
#pragma unroll
  for (int i = 0; i < 4; i++)
#pragma unroll
    for (int j = 0; j < 4; j++) acc[i][j] = (f32x4){0.f, 0.f, 0.f, 0.f};

  const int sr = t >> 3;         // 0..31: row within 32-row group
  const int sc = (t & 7) * 8;    // col (element) within 64

  for (int k0 = 0; k0 < K; k0 += 64) {
    __syncthreads();
#pragma unroll
    for (int i = 0; i < 4; i++) {
      gload16(A + (long)(m0 + i * 32 + sr) * K + k0 + sc, As + (i * 32 + w * 8) * 64);
      gload16(Bt + (long)(n0 + i * 32 + sr) * K + k0 + sc, Bs + (i * 32 + w * 8) * 64);
    }
    __syncthreads();  // compiler emits s_waitcnt vmcnt(0) before barrier
#pragma unroll
    for (int kk = 0; kk < 64; kk += 32) {
      bf16x8 af[4], bfr[4];
#pragma unroll
      for (int i = 0; i < 4; i++)
        af[i] = *(const bf16x8*)(As + (wm + i * 16 + l16) * 64 + kk + quad * 8);
#pragma unroll
      for (int j = 0; j < 4; j++)
        bfr[j] = *(const bf16x8*)(Bs + (wn + j * 16 + l16) * 64 + kk + quad * 8);
#pragma unroll
      for (int i = 0; i < 4; i++)
#pragma unroll
        for (int j = 0; j < 4; j++) acc[i][j] = mfma16(af[i], bfr[j], acc[i][j]);
    }
  }
#pragma unroll
  for (int i = 0; i < 4; i++)
#pragma unroll
    for (int j = 0; j < 4; j++) {
      int col = n0 + wn + j * 16 + l16;
#pragma unroll
      for (int r = 0; r < 4; r++) {
        int row = m0 + wm + i * 16 + quad * 4 + r;
        C[(long)row * N + col] = (CT)acc[i][j][r];
      }
    }
}

// ---------------------------------------------------------------------------
// FUSED: per (b, q-tile of 16): all three logits terms accumulated in LDS
// (fp32, pad-65), softmax, P@a_v. Writes probs (bf16) + out2 (bf16).
// LDS = Ls only (66.5KB) -> 2 blocks/CU. P is written IN-PLACE (bf16) into
// the first 128B of each Ls row by softmax; pav hoists its P fragments to
// registers before overwriting the row region with avT.
// __launch_bounds__(1024, 8): 8 waves/EU = 2 blocks/CU, caps VGPR at 64.
// ---------------------------------------------------------------------------
__global__ __launch_bounds__(1024, 8) void fused_att(
    const bf16_t* __restrict__ Qb, const bf16_t* __restrict__ Kb,
    const float* __restrict__ aqp, const float* __restrict__ akp,
    const float* __restrict__ avp,
    bf16_t* __restrict__ probs, bf16_t* __restrict__ out2) {
  __shared__ float Ls[256 * 65];      // logits [row=q*16+h][k], pad 65 (66.5KB)

  const int id = blockIdx.x;
  const int b = (id & 7) * 16 + ((id >> 3) & 15);  // bijective XCD swizzle
  const int q0 = (id >> 7) * 16;                   // q-tile origin: 0,16,32,48
  const int t = threadIdx.x;
  const int w = t >> 6, lane = t & 63, l16 = lane & 15, quad = lane >> 4;

  // ---- phase cc: head h = w --------------------------------------------
  {
    const int h = w;
    f32x4 acc[4];
#pragma unroll
    for (int j = 0; j < 4; j++) acc[j] = (f32x4){0.f, 0.f, 0.f, 0.f};
    const bf16_t* qb = Qb + (long)(b * Tn + q0 + l16) * Dn + h * HDn;
    const bf16_t* kb = Kb + (long)b * (Tn * Dn) + h * HDn;
#pragma unroll
    for (int kk = 0; kk < 64; kk += 32) {
      bf16x8 af = *(const bf16x8*)(qb + kk + quad * 8);
#pragma unroll
      for (int j = 0; j < 4; j++) {
        bf16x8 bf = *(const bf16x8*)(kb + (long)(j * 16 + l16) * Dn + kk + quad * 8);
        acc[j] = mfma16(af, bf, acc[j]);
      }
    }
#pragma unroll
    for (int j = 0; j < 4; j++)
#pragma unroll
      for (int r = 0; r < 4; r++)
        Ls[((quad * 4 + r) * 16 + h) * 65 + j * 16 + l16] = 0.125f * acc[j][r];
  }
  __syncthreads();

  // ---- phase aq: k = w*4 .. w*4+3 --------------------------------------
  {
    const float* ab = aqp + (long)(b * Tn + q0 + l16) * (Tn * HDn);
    const bf16_t* kb = Kb + (long)b * (Tn * Dn) + l16 * HDn;  // h = l16
#pragma unroll
    for (int kc = 0; kc < 4; kc++) {
      const int k = w * 4 + kc;
      f32x4 acc = (f32x4){0.f, 0.f, 0.f, 0.f};
#pragma unroll
      for (int kk = 0; kk < 64; kk += 32) {
        bf16x8 af = ld8f(ab + k * HDn + kk + quad * 8);
        bf16x8 bf = *(const bf16x8*)(kb + (long)k * Dn + kk + quad * 8);
        acc = mfma16(af, bf, acc);
      }
#pragma unroll
      for (int r = 0; r < 4; r++)
        Ls[((quad * 4 + r) * 16 + l16) * 65 + k] += acc[r];
    }
  }
  __syncthreads();

  // ---- phase ak: q = w --------------------------------------------------
  {
    const int q = w;
    const bf16_t* qb = Qb + (long)(b * Tn + q0 + q) * Dn + l16 * HDn;  // h = l16
    const float* ab = akp + (long)(b * Tn + q0 + q) * (Tn * HDn);
    f32x4 acc[4];
#pragma unroll
    for (int j = 0; j < 4; j++) acc[j] = (f32x4){0.f, 0.f, 0.f, 0.f};
#pragma unroll
    for (int kk = 0; kk < 64; kk += 32) {
      bf16x8 af = *(const bf16x8*)(qb + kk + quad * 8);
#pragma unroll
      for (int j = 0; j < 4; j++) {
        bf16x8 bf = ld8f(ab + (long)(j * 16 + l16) * HDn + kk + quad * 8);
        acc[j] = mfma16(af, bf, acc[j]);
      }
    }
#pragma unroll
    for (int j = 0; j < 4; j++)
#pragma unroll
      for (int r = 0; r < 4; r++)
        Ls[(q * 16 + quad * 4 + r) * 65 + j * 16 + l16] += acc[j][r];
  }
  __syncthreads();

  // ---- softmax: row r = t>>2 (q=r>>4, h=r&15), k-range (t&3)*16 --------
  // P written in-place (bf16) into the row's first 128B. Safe: rows are
  // touched only by 4 lanes of the SAME wave; the stores data-depend on the
  // shuffled reductions, so all row reads precede all row writes.
  {
    const int r = t >> 2, qq = t & 3;
    const float* rowf = Ls + r * 65 + qq * 16;
    float v[16];
#pragma unroll
    for (int i = 0; i < 16; i++) v[i] = rowf[i];
    float m = v[0];
#pragma unroll
    for (int i = 1; i < 16; i++) m = fmaxf(m, v[i]);
    m = fmaxf(m, __shfl_xor(m, 1));
    m = fmaxf(m, __shfl_xor(m, 2));
    float s = 0.f;
#pragma unroll
    for (int i = 0; i < 16; i++) { v[i] = __expf(v[i] - m); s += v[i]; }
    s += __shfl_xor(s, 1);
    s += __shfl_xor(s, 2);
    const float inv = 1.0f / s;
    const int q = r >> 4, h = r & 15;
    bf16_t* prow = (bf16_t*)(Ls + r * 65) + qq * 16;
    bf16_t* pg = probs + ((long)(b * Hn + h) * Tn + q0 + q) * Tn + qq * 16;
#pragma unroll
    for (int c = 0; c < 2; c++) {
      bf16x8 pv8;
#pragma unroll
      for (int ee = 0; ee < 8; ee++) pv8[ee] = (bf16_t)(v[c * 8 + ee] * inv);
      *(bf16x8*)(pg + c * 8) = pv8;
      *(bf16x8*)(prow + c * 8) = pv8;
    }
  }
  // NO barrier: wave w only consumes rows [16w,16w+16) it wrote itself.

  // ---- pav: q = w. avT reuses THIS WAVE'S dead Ls rows -----------------
  {
    const int q = w;
    // hoist P fragments to regs BEFORE avT overwrites the row region
    const bf16_t* prow = (const bf16_t*)(Ls + (q * 16 + l16) * 65);
    bf16x8 paf0 = *(const bf16x8*)(prow + quad * 8);         // k 0..31 slice
    bf16x8 paf1 = *(const bf16x8*)(prow + 32 + quad * 8);    // k 32..63 slice
    asm volatile("s_waitcnt lgkmcnt(0)" ::: "memory");
    __builtin_amdgcn_sched_barrier(0);

    bf16_t* avT = (bf16_t*)(Ls + 16 * w * 65);  // 4160B avail, 4096 used
    const float* src = avp + (long)(b * Tn + q0 + q) * (Tn * HDn) + lane * HDn;
    f32x4 acc[4];
#pragma unroll
    for (int j = 0; j < 4; j++) acc[j] = (f32x4){0.f, 0.f, 0.f, 0.f};
#pragma unroll
    for (int half = 0; half < 2; half++) {
      // stage a_v[d = half*32+0..31][k=lane] -> avT (chunk-swizzled, bf16)
#pragma unroll
      for (int c = 0; c < 8; c++) {
        float4 vv = *(const float4*)(src + half * 32 + c * 4);
#pragma unroll
        for (int ee = 0; ee < 4; ee++) {
          int dl = c * 4 + ee;
          avT[dl * 64 + (((lane >> 3) ^ dl) & 7) * 8 + (lane & 7)] =
              (bf16_t)(&vv.x)[ee];
        }
      }
      asm volatile("s_waitcnt lgkmcnt(0)" ::: "memory");
      __builtin_amdgcn_sched_barrier(0);
#pragma unroll
      for (int kk = 0; kk < 64; kk += 32) {
        bf16x8 af = (kk == 0) ? paf0 : paf1;
        const int cg = (kk >> 3) + quad;
#pragma unroll
        for (int jj = 0; jj < 2; jj++) {
          int j = half * 2 + jj;
          int dl = jj * 16 + l16;  // d within this half
          bf16x8 bf = *(const bf16x8*)(avT + dl * 64 + ((cg ^ (dl & 7))) * 8);
          acc[j] = mfma16(af, bf, acc[j]);
        }
      }
      if (half == 0) {  // drain avT reads before next half's staging writes
        asm volatile("s_waitcnt lgkmcnt(0)" ::: "memory");
        __builtin_amdgcn_sched_barrier(0);
      }
    }
    bf16_t* ob = out2 + (long)(b * Tn + q0 + q) * Dn;
#pragma unroll
    for (int j = 0; j < 4; j++)
#pragma unroll
      for (int r = 0; r < 4; r++)
        ob[(quad * 4 + r) * HDn + j * 16 + l16] = (bf16_t)acc[j][r];
  }
}

// ---------------------------------------------------------------------------
// K4: per (b,h): attn[b,q,h,d] = probs[b,h] @ V[b,:,h,:] + out2[b,q,h,d]
// ---------------------------------------------------------------------------
__global__ __launch_bounds__(256) void pv_out(const bf16_t* __restrict__ probs,
                                              const bf16_t* __restrict__ V,
                                              const bf16_t* __restrict__ out2,
                                              bf16_t* __restrict__ attn) {
  const int h = blockIdx.x, b = blockIdx.y;
  __shared__ bf16_t VT[64][72];
  const int t = threadIdx.x, w = t >> 6, lane = t & 63;
  const int l16 = lane & 15, quad = lane >> 4;

  {  // V[b,k,h,d] -> VT[d][k]
    const bf16_t* src = V + (long)b * (Tn * Dn) + h * HDn;
    int k = t & 63, d0 = (t >> 6) * 16;
    union { uint4 u; unsigned short s[8]; } v0, v1;
    v0.u = *(const uint4*)(src + (long)k * Dn + d0);
    v1.u = *(const uint4*)(src + (long)k * Dn + d0 + 8);
    unsigned short* lds = (unsigned short*)&VT[0][0];
#pragma unroll
    for (int j = 0; j < 8; j++) lds[(d0 + j) * 72 + k] = v0.s[j];
#pragma unroll
    for (int j = 0; j < 8; j++) lds[(d0 + 8 + j) * 72 + k] = v1.s[j];
  }
  __syncthreads();

  const bf16_t* pbase = probs + ((long)(b * Hn + h) * Tn) * Tn;
  f32x4 acc[4];
#pragma unroll
  for (int j = 0; j < 4; j++) acc[j] = (f32x4){0.f, 0.f, 0.f, 0.f};
#pragma unroll
  for (int kk = 0; kk < 64; kk += 32) {
    bf16x8 af = *(const bf16x8*)(pbase + (long)(w * 16 + l16) * Tn + kk + quad * 8);
#pragma unroll
    for (int j = 0; j < 4; j++) {
      bf16x8 bfr = *(const bf16x8*)(&VT[j * 16 + l16][kk + quad * 8]);
      acc[j] = mfma16(af, bfr, acc[j]);
    }
  }
#pragma unroll
  for (int j = 0; j < 4; j++)
#pragma unroll
    for (int r = 0; r < 4; r++) {
      int qrow = w * 16 + quad * 4 + r, d = j * 16 + l16;
      long idx = (long)(b * Tn + qrow) * Dn + h * HDn + d;
      attn[idx] = (bf16_t)(acc[j][r] + (float)out2[idx]);
    }
}

// ---------------------------------------------------------------------------
extern "C" void kernel_launch(void* const* d_in, const int* in_sizes, int n_in,
                              void* d_out, int out_size, void* d_ws, size_t ws_size,
                              hipStream_t stream) {
  const float* x  = (const float*)d_in[0];
  const float* aq = (const float*)d_in[1];
  const float* ak = (const float*)d_in[2];
  const float* av = (const float*)d_in[3];
  const float* Wq = (const float*)d_in[4];
  const float* Wk = (const float*)d_in[5];
  const float* Wv = (const float*)d_in[6];
  const float* Wo = (const float*)d_in[7];
  float* out = (float*)d_out;

  char* ws = (char*)d_ws;
  const size_t MB = 1024 * 1024;
  bf16_t* WqT    = (bf16_t*)(ws + 0 * MB);     // 2MB each
  bf16_t* WkT    = (bf16_t*)(ws + 2 * MB);
  bf16_t* WvT    = (bf16_t*)(ws + 4 * MB);
  bf16_t* WoT    = (bf16_t*)(ws + 6 * MB);
  bf16_t* xb     = (bf16_t*)(ws + 8 * MB);     // [B,T,D] bf16 16MB
  bf16_t* Qb     = (bf16_t*)(ws + 24 * MB);    // [B,T,H,HD] 16MB
  bf16_t* Kb     = (bf16_t*)(ws + 40 * MB);
  bf16_t* Vb     = (bf16_t*)(ws + 56 * MB);
  bf16_t* probs  = (bf16_t*)(ws + 72 * MB);    // [B,H,T,T] 16MB
  bf16_t* out2   = (bf16_t*)(ws + 88 * MB);    // [B,T,H,HD] 16MB
  bf16_t* attn   = (bf16_t*)(ws + 104 * MB);   // [B,T,D] 16MB -> 120MB total

  dim3 blk(256);
  convert_bf16<<<dim3(4096), blk, 0, stream>>>(x, xb);
  transpose_mat<<<dim3(16, 16), blk, 0, stream>>>(Wq, WqT);
  transpose_mat<<<dim3(16, 16), blk, 0, stream>>>(Wk, WkT);
  transpose_mat<<<dim3(16, 16), blk, 0, stream>>>(Wv, WvT);
  transpose_mat<<<dim3(16, 16), blk, 0, stream>>>(Wo, WoT);

  gemm_bt<bf16_t><<<dim3(8, 64), blk, 0, stream>>>(xb, WqT, Qb, Bn * Tn, Dn, Dn);
  gemm_bt<bf16_t><<<dim3(8, 64), blk, 0, stream>>>(xb, WkT, Kb, Bn * Tn, Dn, Dn);
  gemm_bt<bf16_t><<<dim3(8, 64), blk, 0, stream>>>(xb, WvT, Vb, Bn * Tn, Dn, Dn);

  fused_att<<<dim3(512), dim3(1024), 0, stream>>>(Qb, Kb, aq, ak, av, probs, out2);

  pv_out<<<dim3(Hn, Bn), blk, 0, stream>>>(probs, Vb, out2, attn);

  gemm_bt<float><<<dim3(8, 64), blk, 0, stream>>>(attn, WoT, out, Bn * Tn, Dn, Dn);
}